// Round 9
// baseline (126.512 us; speedup 1.0000x reference)
//
#include <hip/hip_runtime.h>
#include <hip/hip_fp16.h>
#include <cstdint>

// Problem constants
#define BB 8
#define NN 256
#define NC 5
#define NH 8
#define DIM 512
#define HD 64

typedef _Float16 half_t;
typedef _Float16 h8 __attribute__((ext_vector_type(8)));
typedef _Float16 h4 __attribute__((ext_vector_type(4)));
typedef float f4 __attribute__((ext_vector_type(4)));
typedef uint32_t u4v __attribute__((ext_vector_type(4)));

__device__ __forceinline__ f4 mfma16(h8 a, h8 b, f4 c) {
  return __builtin_amdgcn_mfma_f32_16x16x32_f16(a, b, c, 0, 0, 0);
}

static __device__ const h8 HZERO = {(_Float16)0, (_Float16)0, (_Float16)0, (_Float16)0,
                                    (_Float16)0, (_Float16)0, (_Float16)0, (_Float16)0};

__device__ __forceinline__ h8 relu_pos_h8(h8 x) {
#if __has_builtin(__builtin_elementwise_max)
  return __builtin_elementwise_max(x, HZERO);
#else
  u4v u = __builtin_bit_cast(u4v, x);
  const u4v k1 = {0x00010001u, 0x00010001u, 0x00010001u, 0x00010001u};
  u4v s = (u >> 15) & k1;
  u4v m = (s << 16) - s;
  u = u & ~m;
  return __builtin_bit_cast(h8, u);
#endif
}

__device__ __forceinline__ h8 relu_neg_h8(h8 x) {
#if __has_builtin(__builtin_elementwise_max)
  return __builtin_elementwise_max(-x, HZERO);
#else
  u4v u = __builtin_bit_cast(u4v, x);
  const u4v k1 = {0x00010001u, 0x00010001u, 0x00010001u, 0x00010001u};
  const u4v ks = {0x80008000u, 0x80008000u, 0x80008000u, 0x80008000u};
  u4v s = (u >> 15) & k1;
  u4v m = (s << 16) - s;
  u = (u ^ ks) & m;
  return __builtin_bit_cast(h8, u);
#endif
}

// Raw barrier: waits LDS only, does NOT drain vmcnt (global stores stay in flight).
__device__ __forceinline__ void barrier_lds() {
  __builtin_amdgcn_sched_barrier(0);
  asm volatile("s_waitcnt lgkmcnt(0)" ::: "memory");
  __builtin_amdgcn_s_barrier();
  asm volatile("" ::: "memory");
  __builtin_amdgcn_sched_barrier(0);
}

// ---------------------------------------------------------------------------
// K0: convert x, anchors, qk_w, v_w, proj_w to fp16 (one f4->h4 per thread).
// ---------------------------------------------------------------------------
__global__ __launch_bounds__(256) void cvt_all(const float* __restrict__ x,
                                               const float* __restrict__ anchors,
                                               const float* __restrict__ qk_w,
                                               const float* __restrict__ v_w,
                                               const float* __restrict__ proj_w,
                                               half_t* __restrict__ x_h,
                                               half_t* __restrict__ anc_h,
                                               half_t* __restrict__ qk_h,
                                               half_t* __restrict__ v_wh,
                                               half_t* __restrict__ pw_h) {
  int i = blockIdx.x * 256 + threadIdx.x;
  const float* src;
  half_t* dst;
  int off;
  if (i < 262144)      { src = x;       dst = x_h;   off = i; }
  else if (i < 425984) { src = anchors; dst = anc_h; off = i - 262144; }
  else if (i < 491520) { src = qk_w;    dst = qk_h;  off = i - 425984; }
  else if (i < 557056) { src = v_w;     dst = v_wh;  off = i - 491520; }
  else                 { src = proj_w;  dst = pw_h;  off = i - 557056; }
  float4 v = ((const float4*)src)[off];
  h4 o;
  o[0] = (_Float16)v.x; o[1] = (_Float16)v.y; o[2] = (_Float16)v.z; o[3] = (_Float16)v.w;
  ((h4*)dst)[off] = o;
}

// ---------------------------------------------------------------------------
// K1: all three projections (pure fp16 operands).
// ---------------------------------------------------------------------------
__global__ __launch_bounds__(256) void proj_all(const half_t* __restrict__ x_h,
                                                const half_t* __restrict__ anc_h,
                                                const half_t* __restrict__ qk_h,
                                                const half_t* __restrict__ v_wh,
                                                half_t* __restrict__ q_h,
                                                half_t* __restrict__ k_h,
                                                half_t* __restrict__ vT) {
  const int bx = blockIdx.x, by = blockIdx.y;
  const int tid = threadIdx.x;
  const int w = tid >> 6, lane = tid & 63;
  const int lr = lane & 15, lk = (lane >> 4) * 8, lg = lane >> 4;

  const half_t* A;
  const half_t* W;
  int mode, rt0;
  if (bx < 32)      { A = x_h;   W = qk_h; mode = 0; rt0 = bx * 64; }
  else if (bx < 52) { A = anc_h; W = qk_h; mode = 1; rt0 = (bx - 32) * 64; }
  else              { A = x_h;   W = v_wh; mode = 2; rt0 = (bx - 52) * 64; }

  const int row0 = rt0 + w * 16;
  const int col0 = by * 64;
  const f4 fz = {0.f, 0.f, 0.f, 0.f};
  f4 acc[4] = {fz, fz, fz, fz};
  const half_t* arow = A + (size_t)(row0 + lr) * DIM;

  if (mode != 2) {
    for (int k0 = 0; k0 < DIM; k0 += 32) {
      h8 a = *(const h8*)(arow + k0 + lk);
#pragma unroll
      for (int ct = 0; ct < 4; ++ct) {
        h8 b = *(const h8*)(W + (size_t)(col0 + ct * 16 + lr) * DIM + k0 + lk);
        acc[ct] = mfma16(a, b, acc[ct]);
      }
    }
    half_t* out = (mode == 0) ? q_h : k_h;
#pragma unroll
    for (int ct = 0; ct < 4; ++ct) {
      int col = col0 + ct * 16 + lr;
#pragma unroll
      for (int r = 0; r < 4; ++r) {
        int row = row0 + lg * 4 + r;
        out[(size_t)row * DIM + col] = (half_t)acc[ct][r];
      }
    }
  } else {
    for (int k0 = 0; k0 < DIM; k0 += 32) {
      h8 a = *(const h8*)(arow + k0 + lk);
#pragma unroll
      for (int ct = 0; ct < 4; ++ct) {
        h8 b = *(const h8*)(W + (size_t)(col0 + ct * 16 + lr) * DIM + k0 + lk);
        acc[ct] = mfma16(b, a, acc[ct]);
      }
    }
    const int xrow = row0 + lr;
#pragma unroll
    for (int ct = 0; ct < 4; ++ct) {
#pragma unroll
      for (int r = 0; r < 4; ++r) {
        int col = col0 + ct * 16 + lg * 4 + r;  // = h*64 + d
        vT[(size_t)col * (BB * NN) + xrow] = (half_t)acc[ct][r];
      }
    }
  }
}

// ---------------------------------------------------------------------------
// K2 v8: ONE block per (b,c,h) task. 1024 thr = 16 waves. Full a0 in LDS.
//  P0: stage kst [256][64] into the UPPER 32KB of the a0s region (a0s is
//      written only after phase 1 -- acc lives in registers).
//  P1: wave w computes a0[16 rows n0=w*16][all 256 m] into 64 VGPRs.
//  P2: write a0s fp16 (full) + a0 fp32 to d_out (once). barrier.
//  P3: S with square tiles: wave (sg=w&7, cg=w>>3) owns [32 n][128 m'];
//      La re-read per kc (live 8 regs); 80 b128 reads / 1.05M MACs.
//  P4: softmax over n per m'-col: wave (max,sum) -> scr[8 sg][256],
//      combine 256 thr, vst staged into dead a0s concurrently.
//  P5: PV per 32-m' panel via per-wave [32][42] bounce; partials of the two
//      cg halves go to U4[task][cg] (reduce_u sums them; no exchange).
// LDS: a0s 128K (kst/vst/pbuf overlays) + scr 16K + scr2 2K = 149,504 B.
// ---------------------------------------------------------------------------
__global__ __launch_bounds__(1024, 4) void fused_attn8(const half_t* __restrict__ q_h,
                                                       const half_t* __restrict__ k_h,
                                                       const half_t* __restrict__ vT,
                                                       const float* __restrict__ weights,
                                                       float* __restrict__ a0_base,
                                                       half_t* __restrict__ U4) {
  extern __shared__ char smem[];
  half_t* a0s = (half_t*)smem;                    // [256][256] swz, 131072 B
  half_t* kst = (half_t*)(smem + 98304);          // overlay: [256][64] swz, 32 KB
  half_t* vst = (half_t*)smem;                    // overlay: [64][256] swz, 32 KB
  half_t* pbuf = (half_t*)(smem + 32768);         // overlay: 16 x [32][42], 43 KB
  float2* scr = (float2*)(smem + 131072);         // [8 sg][256 m'], 16384 B
  float2* scr2 = (float2*)(smem + 147456);        // [256 m'] (gm,sg), 2048 B

  const int id = blockIdx.x;  // 320
  const int b = id / 40;
  const int rem = id % 40;
  const int c = rem / 8;
  const int h = rem & 7;

  const int tid = threadIdx.x;
  const int w = tid >> 6, lane = tid & 63;
  const int lr = lane & 15, lk = (lane >> 4) * 8, lg = lane >> 4;
  const int n0 = w * 16;           // phase-1 rows
  const int sg = w & 7, cg = w >> 3;

  const half_t* qb = q_h + (size_t)(b * NN) * DIM + h * HD;
  const half_t* kb = k_h + (size_t)(c * NN) * DIM + h * HD;
  const half_t* vTb = vT + (size_t)(h * HD) * (BB * NN) + b * NN;
  float* a0out = a0_base + (size_t)((b * NC + c) * NH + h) * (NN * NN);
  const float wgt = weights[(b * NH + h) * NC + c];

  const f4 fz = {0.f, 0.f, 0.f, 0.f};

  // q fragments for this wave's 16 rows
  h8 qf0 = *(const h8*)(qb + (size_t)(n0 + lr) * DIM + lk);
  h8 qf1 = *(const h8*)(qb + (size_t)(n0 + lr) * DIM + 32 + lk);

  // ---- P0: stage k tile [256][64] (upper 32KB of a0s region) ----
#pragma unroll
  for (int pass = 0; pass < 2; ++pass) {
    int slot = pass * 1024 + tid;
    int row = slot >> 3, k8 = (slot & 7) * 8;
    h8 val = *(const h8*)(kb + (size_t)row * DIM + k8);
    *(h8*)(kst + ((row * 64 + k8) ^ ((row & 7) << 3))) = val;
  }
  barrier_lds();  // A

  // ---- P1: a0[16 rows][256 m] in registers ----
  f4 acc[16];
#pragma unroll
  for (int mt = 0; mt < 16; ++mt) {
    const int krow = mt * 16 + lr;
    h8 kf0 = *(const h8*)(kst + ((krow * 64 + lk) ^ ((krow & 7) << 3)));
    h8 kf1 = *(const h8*)(kst + ((krow * 64 + 32 + lk) ^ ((krow & 7) << 3)));
    acc[mt] = mfma16(kf0, qf0, fz);
    acc[mt] = mfma16(kf1, qf1, acc[mt]);
#pragma unroll
    for (int r = 0; r < 4; ++r) acc[mt][r] *= 0.125f;
  }
  barrier_lds();  // B: all kst reads done

  // ---- P2: write fp16 a0s (full) + fp32 a0 to global (once) ----
  const int na = n0 + lr;
#pragma unroll
  for (int mt = 0; mt < 16; ++mt) {
    const int mb = mt * 16 + lg * 4;
    h4 hv;
#pragma unroll
    for (int r = 0; r < 4; ++r) hv[r] = (_Float16)acc[mt][r];
    *(h4*)(a0s + ((na * NN + mb) ^ ((na & 7) << 3))) = hv;
    *(f4*)(a0out + (size_t)na * NN + mb) = acc[mt];
  }
  barrier_lds();  // C: a0s complete

  // ---- P3: S = relu(-a0) @ relu(a0)^T, wave tile [32 n][128 m'] ----
  f4 sacc[8][2];
#pragma unroll
  for (int ct = 0; ct < 8; ++ct) {
    sacc[ct][0] = fz;
    sacc[ct][1] = fz;
  }
#pragma unroll
  for (int kc = 0; kc < 8; ++kc) {
    const int rl0 = sg * 32 + lr, rl1 = sg * 32 + 16 + lr;
    h8 La0 = relu_neg_h8(*(const h8*)(a0s + ((rl0 * NN + kc * 32 + lk) ^ ((rl0 & 7) << 3))));
    h8 La1 = relu_neg_h8(*(const h8*)(a0s + ((rl1 * NN + kc * 32 + lk) ^ ((rl1 & 7) << 3))));
#pragma unroll
    for (int ct = 0; ct < 8; ++ct) {
      const int rr = cg * 128 + ct * 16 + lr;
      h8 R = relu_pos_h8(*(const h8*)(a0s + ((rr * NN + kc * 32 + lk) ^ ((rr & 7) << 3))));
      sacc[ct][0] = mfma16(La0, R, sacc[ct][0]);
      sacc[ct][1] = mfma16(La1, R, sacc[ct][1]);
    }
  }

  // ---- P4: softmax over n per m'-col ----
  float mw[8];
#pragma unroll
  for (int ct = 0; ct < 8; ++ct) {
    float v = 0.f;  // S >= 0 always
#pragma unroll
    for (int rt = 0; rt < 2; ++rt)
#pragma unroll
      for (int r = 0; r < 4; ++r) v = fmaxf(v, sacc[ct][rt][r]);
    v = fmaxf(v, __shfl_xor(v, 16, 64));
    v = fmaxf(v, __shfl_xor(v, 32, 64));
    mw[ct] = v;
    float s = 0.f;
#pragma unroll
    for (int rt = 0; rt < 2; ++rt)
#pragma unroll
      for (int r = 0; r < 4; ++r) {
        float e = __expf(sacc[ct][rt][r] - v);
        sacc[ct][rt][r] = e;
        s += e;
      }
    s += __shfl_xor(s, 16, 64);
    s += __shfl_xor(s, 32, 64);
    if (lane < 16) {
      float2 t;
      t.x = v;
      t.y = s;
      scr[sg * 256 + cg * 128 + ct * 16 + lr] = t;
    }
  }
  barrier_lds();  // D: scr done, all a0s reads done

  // ---- combine (256 thr) ∥ stage vst [64 d][256 m'] into dead a0s ----
  if (tid < 256) {
    float gm = 0.f;
#pragma unroll
    for (int ww = 0; ww < 8; ++ww) gm = fmaxf(gm, scr[ww * 256 + tid].x);
    float sg2 = 0.f;
#pragma unroll
    for (int ww = 0; ww < 8; ++ww) {
      float2 t = scr[ww * 256 + tid];
      sg2 += t.y * __expf(t.x - gm);
    }
    float2 r;
    r.x = gm;
    r.y = sg2;
    scr2[tid] = r;
  }
#pragma unroll
  for (int pass = 0; pass < 2; ++pass) {
    int slot = pass * 1024 + tid;
    int d = slot >> 5, m8 = (slot & 31) * 8;
    h8 vv = *(const h8*)(vTb + (size_t)d * (BB * NN) + m8);
    *(h8*)(vst + ((d * NN + m8) ^ ((d & 7) << 3))) = vv;
  }
  barrier_lds();  // E: scr2 + vst ready

  // fold fac into P (frees mw afterwards)
#pragma unroll
  for (int ct = 0; ct < 8; ++ct) {
    float2 t = scr2[cg * 128 + ct * 16 + lr];
    float fac = __expf(mw[ct] - t.x) * wgt / t.y;
#pragma unroll
    for (int rt = 0; rt < 2; ++rt)
#pragma unroll
      for (int r = 0; r < 4; ++r) sacc[ct][rt][r] *= fac;
  }

  // ---- P5: PV per 32-m' panel via per-wave [32][42] bounce ----
  half_t* pbw = pbuf + w * 1344;  // [32 m'][42 n-pad]
  f4 uacc[4][2];
#pragma unroll
  for (int dt = 0; dt < 4; ++dt) {
    uacc[dt][0] = fz;
    uacc[dt][1] = fz;
  }
#pragma unroll
  for (int p = 0; p < 4; ++p) {
#pragma unroll
    for (int ctl = 0; ctl < 2; ++ctl) {
      const int ct = p * 2 + ctl;
#pragma unroll
      for (int rt = 0; rt < 2; ++rt) {
        h4 hv;
#pragma unroll
        for (int r = 0; r < 4; ++r) hv[r] = (_Float16)sacc[ct][rt][r];
        *(h4*)(pbw + (ctl * 16 + lr) * 42 + rt * 16 + lg * 4) = hv;
      }
    }
    h8 pf0, pf1;
#pragma unroll
    for (int e = 0; e < 8; ++e) {
      pf0[e] = pbw[(lg * 8 + e) * 42 + lr];
      pf1[e] = pbw[(lg * 8 + e) * 42 + 16 + lr];
    }
#pragma unroll
    for (int dt = 0; dt < 4; ++dt) {
      const int dr = dt * 16 + lr;
      h8 vf = *(const h8*)(vst + ((dr * NN + cg * 128 + p * 32 + lg * 8) ^ ((dr & 7) << 3)));
      uacc[dt][0] = mfma16(vf, pf0, uacc[dt][0]);
      uacc[dt][1] = mfma16(vf, pf1, uacc[dt][1]);
    }
  }

  // ---- store partial U4 (fp16): [n][d], slot = cg ----
  half_t* U4b = U4 + (size_t)(((b * NC + c) * NH + h) * 2 + cg) * (NN * HD);
#pragma unroll
  for (int dt = 0; dt < 4; ++dt)
#pragma unroll
    for (int nt = 0; nt < 2; ++nt) {
      int n = sg * 32 + nt * 16 + lr;
      h4 hv;
#pragma unroll
      for (int r = 0; r < 4; ++r) hv[r] = (_Float16)uacc[dt][nt][r];
      *(h4*)(U4b + (size_t)n * HD + dt * 16 + lg * 4) = hv;
    }
}

// ---------------------------------------------------------------------------
// K3: out_head[b,h] = sum over (c, slot) of U4 partials
// ---------------------------------------------------------------------------
__global__ __launch_bounds__(256) void reduce_u(const half_t* __restrict__ U4,
                                                half_t* __restrict__ out_head) {
  int t = blockIdx.x * 256 + threadIdx.x;  // 131072 threads
  int bh = t >> 11;
  int e = (t & 2047) * 8;
  int b = bh >> 3, h = bh & 7;
  float acc[8] = {0.f, 0.f, 0.f, 0.f, 0.f, 0.f, 0.f, 0.f};
#pragma unroll
  for (int c = 0; c < NC; ++c)
#pragma unroll
    for (int qq = 0; qq < 2; ++qq) {
      h8 u = *(const h8*)(U4 + (size_t)(((b * NC + c) * NH + h) * 2 + qq) * (NN * HD) + e);
#pragma unroll
      for (int j = 0; j < 8; ++j) acc[j] += (float)u[j];
    }
  h8 o;
#pragma unroll
  for (int j = 0; j < 8; ++j) o[j] = (_Float16)acc[j];
  *(h8*)(out_head + (size_t)bh * (NN * HD) + e) = o;
}

// ---------------------------------------------------------------------------
// K4: out0 = reshape(out_head) @ pw_h^T + proj_b  (fp16 weights)
// ---------------------------------------------------------------------------
__global__ __launch_bounds__(256) void out_proj(const half_t* __restrict__ out_head,
                                                const half_t* __restrict__ pw_h,
                                                const float* __restrict__ pb,
                                                float* __restrict__ out0) {
  const int tid = threadIdx.x;
  const int w = tid >> 6, lane = tid & 63;
  const int lr = lane & 15, lk = (lane >> 4) * 8, lg = lane >> 4;
  const int row0 = blockIdx.x * 64 + w * 16;
  const int col0 = blockIdx.y * 64;
  const int r_ = row0 + lr;
  const int b = r_ >> 8, i = r_ & 255;
  const int hh = i >> 5;
  const f4 fz = {0.f, 0.f, 0.f, 0.f};
  f4 acc[4] = {fz, fz, fz, fz};
  for (int k0 = 0; k0 < DIM; k0 += 32) {
    const int k = k0 + lk;
    const int n = ((i & 31) << 3) | (k >> 6);
    const int d = k & 63;
    h8 a = *(const h8*)(out_head + (size_t)((b * NH + hh) * NN + n) * HD + d);
#pragma unroll
    for (int ct = 0; ct < 4; ++ct) {
      h8 bf = *(const h8*)(pw_h + (size_t)(col0 + ct * 16 + lr) * DIM + k0 + lk);
      acc[ct] = mfma16(a, bf, acc[ct]);
    }
  }
#pragma unroll
  for (int ct = 0; ct < 4; ++ct) {
    int col = col0 + ct * 16 + lr;
    float bias = pb[col];
#pragma unroll
    for (int r = 0; r < 4; ++r) {
      int row = row0 + lg * 4 + r;
      out0[(size_t)row * DIM + col] = acc[ct][r] + bias;
    }
  }
}

// ---------------------------------------------------------------------------
extern "C" void kernel_launch(void* const* d_in, const int* in_sizes, int n_in,
                              void* d_out, int out_size, void* d_ws, size_t ws_size,
                              hipStream_t stream) {
  const float* x = (const float*)d_in[0];
  const float* anchors = (const float*)d_in[1];
  const float* weights = (const float*)d_in[2];
  const float* qk_w = (const float*)d_in[3];
  const float* v_w = (const float*)d_in[4];
  const float* proj_w = (const float*)d_in[5];
  const float* proj_b = (const float*)d_in[6];

  float* out0 = (float*)d_out;                       // [8,256,512]
  float* a0_out = out0 + (size_t)BB * NN * DIM;      // [8,5,8,256,256]

  char* ws = (char*)d_ws;
  const size_t MB = 1024 * 1024;
  // Region 0..20MB: fp16 staging (dead before fused_attn8) then U4 overlay.
  half_t* x_h   = (half_t*)(ws);                  // 2 MB
  half_t* anc_h = (half_t*)(ws + 2 * MB);         // 1.25 MB
  half_t* qk_h  = (half_t*)(ws + 3407872);        // 0.5 MB
  half_t* v_wh  = (half_t*)(ws + 3932160);        // 0.5 MB
  half_t* U4    = (half_t*)(ws);                  // 20 MB (overlay)
  // Persistent region 20..28MB:
  half_t* pw_h     = (half_t*)(ws + 20 * MB);           // 0.5 MB
  half_t* q_h      = (half_t*)(ws + 20 * MB + 524288);  // 2 MB
  half_t* k_h      = (half_t*)(ws + 22 * MB + 524288);  // 1.25 MB
  half_t* vT       = (half_t*)(ws + 24 * MB);           // 2 MB
  half_t* out_head = (half_t*)(ws + 26 * MB);           // 2 MB

  cvt_all<<<dim3(2432), 256, 0, stream>>>(x, anchors, qk_w, v_w, proj_w,
                                          x_h, anc_h, qk_h, v_wh, pw_h);

  proj_all<<<dim3(84, 8), 256, 0, stream>>>(x_h, anc_h, qk_h, v_wh, q_h, k_h, vT);

  const size_t lds_bytes = 131072 + 16384 + 2048;  // 149,504 B
  fused_attn8<<<dim3(BB * NC * NH), 1024, lds_bytes, stream>>>(q_h, k_h, vT, weights,
                                                               a0_out, U4);

  reduce_u<<<dim3(512), 256, 0, stream>>>(U4, out_head);

  out_proj<<<dim3(32, 8), 256, 0, stream>>>(out_head, pw_h, proj_b, out0);

  (void)in_sizes; (void)n_in; (void)out_size; (void)ws_size;
}